// Round 8
// baseline (127.154 us; speedup 1.0000x reference)
//
#include <hip/hip_runtime.h>
#include <hip/hip_bf16.h>
#include <stdint.h>

#define UNITS 1024
#define IDIM  512
#define BATCH 2048
#define KTOT  1536   // UNITS + IDIM
#define NGATE 4096   // 4*UNITS
#define NKK   48     // KTOT / 32 k-chunks
#define NITER 24     // K-loop iters (2 kk per iter)

typedef short bf16x8 __attribute__((ext_vector_type(8)));   // 8 bf16 = 4 VGPRs
typedef float f32x4  __attribute__((ext_vector_type(4)));

#define AS3(p) ((__attribute__((address_space(3))) void*)(p))
#define AS1(p) ((const __attribute__((address_space(1))) void*)(p))

union P8 { bf16x8 v; __hip_bfloat16 e[8]; };

// Fragment-ordered layouts (unchanged from R7, correctness-proven):
//   A2: frag(ii,kk) at [(ii*NKK + kk)*64 + L] * 16B ; lane L holds
//       A[ii*16 + (L&15)][kk*32 + (L>>4)*8 .. +8]   (ii = row/16, 128 total)
//   Wt2: frag(jj,kk) likewise (jj = W^T row / 16, 256 total).
// Every fragment is 1KB contiguous -> coalesced dwordx4 per lane, and
// global_load_lds staging of one fragment is a single wave-instr.

#define NBLK_A 1536
#define NBLK_T 3072

__global__ __launch_bounds__(256) void prep(
    const float* __restrict__ x, const float* __restrict__ h,
    const float* __restrict__ W,
    bf16x8* __restrict__ A2, bf16x8* __restrict__ Wt2) {
  __shared__ float tile[32][65];
  const int tid = threadIdx.x;
  if (blockIdx.x < NBLK_A) {
    const int gid = blockIdx.x * 256 + tid;   // one 16B fragment-slice each
    const int f  = gid >> 6;                  // fragment 0..6143 (128 ii x 48 kk)
    const int L  = gid & 63;
    const int ii = f / NKK;
    const int kk = f - ii * NKK;
    const int r  = ii * 16 + (L & 15);
    const int k  = kk * 32 + (L >> 4) * 8;
    const float* src = (k < UNITS) ? h + (size_t)r * UNITS + k
                                   : x + (size_t)r * IDIM + (k - UNITS);
    const float4 v0 = ((const float4*)src)[0];
    const float4 v1 = ((const float4*)src)[1];
    P8 o;
    o.e[0] = __float2bfloat16(v0.x); o.e[1] = __float2bfloat16(v0.y);
    o.e[2] = __float2bfloat16(v0.z); o.e[3] = __float2bfloat16(v0.w);
    o.e[4] = __float2bfloat16(v1.x); o.e[5] = __float2bfloat16(v1.y);
    o.e[6] = __float2bfloat16(v1.z); o.e[7] = __float2bfloat16(v1.w);
    A2[gid] = o.v;                            // contiguous 1KB per wave
  } else {
    const int b  = blockIdx.x - NBLK_A;   // 0..3071
    const int kb = b >> 7;                // 0..23
    const int nb = b & 127;               // 0..127
    const int k0 = kb * 64, n0 = nb * 32;
    const int n4 = (tid & 7) * 4;
    const int kk = tid >> 3;              // 0..31
#pragma unroll
    for (int rr = 0; rr < 64; rr += 32) {
      const float4 v = *(const float4*)(W + (size_t)(k0 + kk + rr) * NGATE + n0 + n4);
      tile[n4 + 0][kk + rr] = v.x; tile[n4 + 1][kk + rr] = v.y;
      tile[n4 + 2][kk + rr] = v.z; tile[n4 + 3][kk + rr] = v.w;
    }
    __syncthreads();
    const int L    = tid & 63;
    const int half = tid >> 6;            // 0..3
    const int jl   = half >> 1;           // jj local
    const int kl   = half & 1;            // kk local
    const int nloc = (L & 15) + jl * 16;  // 0..31
    const int kloc = kl * 32 + (L >> 4) * 8;
    P8 o;
#pragma unroll
    for (int j = 0; j < 8; ++j) o.e[j] = __float2bfloat16(tile[nloc][kloc + j]);
    const int jj = (n0 >> 4) + jl;        // 0..255
    const int kc = (k0 >> 5) + kl;        // 0..47
    Wt2[(size_t)(jj * NKK + kc) * 64 + L] = o.v;
  }
}

// ---------------------------------------------------------------------------
// R8 GEMM: hybrid operand paths to split fragment-byte traffic across L2 AND
// LDS (R4-R7 post-mortem: all structures hit ~43us = fragment-BW wall when
// one memory carries everything).
//   B: staged in LDS once per block (kills 4-way inter-wave dup; L2 B-traffic
//      /4), double-buffered, 16 contiguous 1KB global_load_lds per iter.
//   A: direct L2->VGPR coalesced fragment loads (R7 path), reg-double-buffered
//      -- no LDS round trip, partial-vmcnt pipelined by the compiler.
// Per CU-iter: L2 ~96KB, LDS ~96KB (parallel pipes), MFMA 310cyc/SIMD.
// Block 128 rows x 32 units x 4 gates; waves 2x2, wave 64x64, acc[4][4].
// ds_read of a fragment is lane-contiguous b128 (conflict-free, m134).
// Grid 512, 2 blocks/CU; one barrier per iter, drain covered by compute.
// XCD: bi%8 = ub%8 -> each XCD's B slice 1.57MB L2-resident.
// ---------------------------------------------------------------------------
__global__ __launch_bounds__(256, 2) void lstm_gemm(
    const bf16x8* __restrict__ A2,
    const bf16x8* __restrict__ Wt2,
    const float* __restrict__ c_tm1,
    float* __restrict__ out) {
  __shared__ __attribute__((aligned(128))) char lds[2 * 16384];  // B0 B1

  const int tid  = threadIdx.x;
  const int w    = tid >> 6;     // wave 0..3 (uniform)
  const int lane = tid & 63;
  const int quad = lane >> 4;
  const int m16  = lane & 15;
  const int wr   = w >> 1;       // row half (0,1)
  const int wu   = w & 1;        // unit half (0,1)

  const int mb = blockIdx.x >> 5;   // 0..15
  const int ub = blockIdx.x & 31;   // 0..31  (XCD = bi%8 = ub%8)
  const int m0 = mb * 128;
  const int u0 = ub * 32;

  // B staging: 16 fragments (16KB) per iter, 4 wave-instrs per wave.
  // idx = s*4 + w (wave-uniform); f = idx>>1 selects (g = f>>1, par = f&1),
  // t = idx&1 selects the kk within the iter's kk-pair.
  const bf16x8* bsrc[4];
  int bdst[4];
#pragma unroll
  for (int s = 0; s < 4; ++s) {
    const int idx = s * 4 + w;
    const int f   = idx >> 1;
    const int t   = idx & 1;
    const int jj  = (f >> 1) * 64 + ub * 2 + (f & 1);
    bsrc[s] = Wt2 + (size_t)(jj * NKK + t) * 64 + lane;
    bdst[s] = idx * 1024;
  }

  // A fragment offsets (16B units); step per kk = 64.
  size_t aoff[4];
  const int ii0 = mb * 8 + wr * 4;
#pragma unroll
  for (int i = 0; i < 4; ++i)
    aoff[i] = (size_t)((ii0 + i) * NKK) * 64 + lane;

  f32x4 acc[4][4];
#pragma unroll
  for (int i = 0; i < 4; ++i)
#pragma unroll
    for (int g = 0; g < 4; ++g) {
      f32x4 z = {0.f, 0.f, 0.f, 0.f};
      acc[i][g] = z;
    }

  bf16x8 a[2][4][2];   // [buf][i][t] register-dbuf A fragments

  // prologue: stage B(it=0) into buf0, load a[0] (kk 0,1)
#pragma unroll
  for (int s = 0; s < 4; ++s)
    __builtin_amdgcn_global_load_lds(AS1(bsrc[s]), AS3(lds + bdst[s]), 16, 0, 0);
#pragma unroll
  for (int t = 0; t < 2; ++t)
#pragma unroll
    for (int i = 0; i < 4; ++i) a[0][i][t] = A2[aoff[i] + t * 64];
  __syncthreads();

  for (int it = 0; it < NITER; ++it) {
    const int cur = it & 1;
    const int nxt = cur ^ 1;
    // prefetch iter it+1: B -> LDS[nxt], A -> a[nxt]  (issued before compute)
    if (it < NITER - 1) {
      const int kk = (it + 1) * 2;
#pragma unroll
      for (int s = 0; s < 4; ++s)
        __builtin_amdgcn_global_load_lds(AS1(bsrc[s] + (size_t)kk * 64),
                                         AS3(lds + nxt * 16384 + bdst[s]), 16, 0, 0);
#pragma unroll
      for (int t = 0; t < 2; ++t)
#pragma unroll
        for (int i = 0; i < 4; ++i) a[nxt][i][t] = A2[aoff[i] + (size_t)(kk + t) * 64];
    }
    // compute iter `it`: b-frags from LDS[cur] (lane-contiguous b128), a from regs
    const char* bbuf = lds + cur * 16384;
#pragma unroll
    for (int t = 0; t < 2; ++t) {
      bf16x8 b[4];
#pragma unroll
      for (int g = 0; g < 4; ++g)
        b[g] = *(const bf16x8*)(bbuf + ((g * 2 + wu) * 2 + t) * 1024 + lane * 16);
#pragma unroll
      for (int g = 0; g < 4; ++g)
#pragma unroll
        for (int i = 0; i < 4; ++i)
          acc[i][g] = __builtin_amdgcn_mfma_f32_16x16x32_bf16(a[cur][i][t], b[g],
                                                              acc[i][g], 0, 0, 0);
    }
    __syncthreads();   // single barrier: drains prefetch, fences LDS[cur] reads
  }

  // fused LSTM epilogue -- all 4 gates in-lane
  const int u = u0 + wu * 16 + m16;
#pragma unroll
  for (int i = 0; i < 4; ++i)
#pragma unroll
    for (int reg = 0; reg < 4; ++reg) {
      const int r = m0 + wr * 64 + i * 16 + quad * 4 + reg;
      const float z0 = acc[i][0][reg];   // gate i
      const float z1 = acc[i][1][reg];   // gate f
      const float z2 = acc[i][2][reg];   // c_tilde
      const float z3 = acc[i][3][reg];   // gate o
      const float ig = 1.f / (1.f + __expf(-z0));
      const float fg = 1.f / (1.f + __expf(-z1));
      const float ct = 1.f - 2.f / (__expf(2.f * z2) + 1.f);   // tanh, inf-safe
      const float og = 1.f / (1.f + __expf(-z3));
      const float cc = fg * c_tm1[(size_t)r * UNITS + u] + ig * ct;
      const float hh = og * (1.f - 2.f / (__expf(2.f * cc) + 1.f));
      out[(size_t)r * UNITS + u] = hh;
      out[(size_t)BATCH * UNITS + (size_t)r * UNITS + u] = cc;
    }
}

// ---------------------------------------------------------------------------
// Fallback (only if d_ws too small): naive fp32, correct but slow.
// ---------------------------------------------------------------------------
__global__ __launch_bounds__(256) void lstm_naive(
    const float* __restrict__ x, const float* __restrict__ h,
    const float* __restrict__ c_tm1, const float* __restrict__ W,
    float* __restrict__ out) {
  int idx = blockIdx.x * 256 + threadIdx.x;
  int r = idx / UNITS;
  int u = idx % UNITS;
  float z[4] = {0.f, 0.f, 0.f, 0.f};
  for (int k = 0; k < KTOT; ++k) {
    float a = (k < UNITS) ? h[(size_t)r * UNITS + k] : x[(size_t)r * IDIM + k - UNITS];
#pragma unroll
    for (int g = 0; g < 4; ++g)
      z[g] += a * W[(size_t)k * NGATE + g * UNITS + u];
  }
  float ig = 1.f / (1.f + __expf(-z[0]));
  float fg = 1.f / (1.f + __expf(-z[1]));
  float ct = 1.f - 2.f / (__expf(2.f * z[2]) + 1.f);
  float og = 1.f / (1.f + __expf(-z[3]));
  float cc = fg * c_tm1[(size_t)r * UNITS + u] + ig * ct;
  float hh = og * (1.f - 2.f / (__expf(2.f * cc) + 1.f));
  out[(size_t)r * UNITS + u] = hh;
  out[(size_t)BATCH * UNITS + (size_t)r * UNITS + u] = cc;
}

extern "C" void kernel_launch(void* const* d_in, const int* in_sizes, int n_in,
                              void* d_out, int out_size, void* d_ws, size_t ws_size,
                              hipStream_t stream) {
  const float* x = (const float*)d_in[0];   // [2048][512]
  const float* h = (const float*)d_in[1];   // [2048][1024]
  const float* c = (const float*)d_in[2];   // [2048][1024]
  const float* W = (const float*)d_in[3];   // [1536][4096]
  float* out = (float*)d_out;               // h then c, 2 x [2048][1024]

  const size_t needA  = (size_t)BATCH * KTOT * sizeof(__hip_bfloat16);  // 6.29 MB
  const size_t needWt = (size_t)NGATE * KTOT * sizeof(__hip_bfloat16);  // 12.58 MB
  if (ws_size < needA + needWt) {
    hipLaunchKernelGGL(lstm_naive, dim3((BATCH * UNITS) / 256), dim3(256), 0, stream,
                       x, h, c, W, out);
    return;
  }

  bf16x8* A2  = (bf16x8*)d_ws;
  bf16x8* Wt2 = (bf16x8*)((char*)d_ws + needA);

  hipLaunchKernelGGL(prep, dim3(NBLK_A + NBLK_T), dim3(256), 0, stream, x, h, W, A2, Wt2);
  hipLaunchKernelGGL(lstm_gemm, dim3(512), dim3(256), 0, stream, A2, Wt2, c, out);
}